// Round 1
// baseline (4072.161 us; speedup 1.0000x reference)
//
#include <hip/hip_runtime.h>
#include <math.h>

#define NN 50000
#define NE 800000
#define NF 512
#define NH 128
#define KF 4
#define NC 64
#define LRELU_ALPHA 0.2f
#define EPSF 1e-16f

// ---------------- workspace layout (float offsets) ----------------
#define OFF_H      0LL                                  // h (NN, 512) f32
#define OFF_PT     (OFF_H + (long long)NN * NF)         // P_T (16, 512)
#define OFF_SSRC   (OFF_PT + 16LL * 512)                // (NN,4)
#define OFF_SDST   (OFF_SSRC + (long long)NN * KF)
#define OFF_S1A    (OFF_SDST + (long long)NN * KF)
#define OFF_S2A    (OFF_S1A + (long long)NN * KF)
#define OFF_XO0    (OFF_S2A + (long long)NN * KF)       // (NN,64)
#define OFF_S1O    (OFF_XO0 + (long long)NN * NC)
#define OFF_S2O    (OFF_S1O + NN)
// ---- zeroed-each-call region starts here ----
#define OFF_HP     (OFF_S2O + NN)                       // (NN,512)
#define OFF_ROWSUM (OFF_HP + (long long)NN * NF)        // (NN,4)
#define OFF_HP2    (OFF_ROWSUM + (long long)NN * KF)    // (NN,64)
#define OFF_RS2    (OFF_HP2 + (long long)NN * NC)       // (NN,)
#define OFF_ATT    (OFF_RS2 + NN)                       // double (2 floats), 8B-aligned
#define WS_FLOATS  (OFF_ATT + 2)

// ---------------------------------------------------------------------------
// K1: projected routing vectors. P_T[t][f], t: 0..3 = P_src(k), 4..7 = P_dst(k),
// 8..11 = Q1(k) (a_att first half), 12..15 = Q2(k).
// s_src[n][k] = x[n]·P_src[k] is mathematically identical (up to f32 rounding)
// to the reference's h @ a_k[:, :512].T.
__global__ void precompute_P(const float* __restrict__ Wks,
                             const float* __restrict__ a_k,
                             const float* __restrict__ a_att,
                             float* __restrict__ P_T) {
    int f = threadIdx.x;  // 0..511
    for (int k = 0; k < KF; ++k) {
        float ps = 0.f, pd = 0.f;
        for (int c = 0; c < 512; ++c) {
            float w = Wks[(size_t)(c >> 7) * (NF * NH) + (size_t)f * NH + (c & 127)];
            ps += w * a_k[k * 1024 + c];
            pd += w * a_k[k * 1024 + 512 + c];
        }
        float q1 = 0.f, q2 = 0.f;
        for (int j = 0; j < NH; ++j) {
            float w = Wks[(size_t)k * (NF * NH) + (size_t)f * NH + j];
            q1 += w * a_att[k * 256 + j];
            q2 += w * a_att[k * 256 + 128 + j];
        }
        P_T[(0 + k) * 512 + f]  = ps;
        P_T[(4 + k) * 512 + f]  = pd;
        P_T[(8 + k) * 512 + f]  = q1;
        P_T[(12 + k) * 512 + f] = q2;
    }
}

// ---------------------------------------------------------------------------
// K2: s-values = x @ P_T^T. One wave per node. P_T staged in LDS (32KB).
__global__ __launch_bounds__(256) void compute_svals(
        const float* __restrict__ x, const float* __restrict__ P_T,
        float* __restrict__ s_src, float* __restrict__ s_dst,
        float* __restrict__ s1a, float* __restrict__ s2a) {
    __shared__ float Pl[16 * 512];
    for (int i = threadIdx.x; i < 16 * 512; i += 256) Pl[i] = P_T[i];
    __syncthreads();
    int w = threadIdx.x >> 6, lane = threadIdx.x & 63;
    int n = blockIdx.x * 4 + w;
    if (n >= NN) return;
    float acc[16];
#pragma unroll
    for (int t = 0; t < 16; ++t) acc[t] = 0.f;
    const float* xr = x + (size_t)n * NF;
#pragma unroll
    for (int i = 0; i < 8; ++i) {
        int f = i * 64 + lane;
        float xf = xr[f];
#pragma unroll
        for (int t = 0; t < 16; ++t) acc[t] = fmaf(xf, Pl[t * 512 + f], acc[t]);
    }
#pragma unroll
    for (int off = 32; off >= 1; off >>= 1)
#pragma unroll
        for (int t = 0; t < 16; ++t) acc[t] += __shfl_xor(acc[t], off);
    if (lane == 0) {
#pragma unroll
        for (int k = 0; k < 4; ++k) {
            s_src[n * 4 + k] = acc[k];
            s_dst[n * 4 + k] = acc[4 + k];
            s1a[n * 4 + k]   = acc[8 + k];
            s2a[n * 4 + k]   = acc[12 + k];
        }
    }
}

// ---------------------------------------------------------------------------
// K3: h = x @ Wcat (f32). Wcat[f][k*128+j] = Wks[k][f][j]. 64x64 tile, BK=32,
// 256 threads, 4x4 microtile. No fp32 MFMA on CDNA4 -> vector ALU GEMM.
__global__ __launch_bounds__(256) void gemm_h(const float* __restrict__ x,
                                              const float* __restrict__ Wks,
                                              float* __restrict__ h) {
    __shared__ float As[32][64];
    __shared__ float Bs[32][64];
    int m0 = blockIdx.y * 64;
    int n0 = blockIdx.x * 64;
    int kf = n0 >> 7, jb = n0 & 127;
    const float* Bsrc = Wks + (size_t)kf * (NF * NH) + jb;
    int tid = threadIdx.x;
    int tm = tid >> 4, tn = tid & 15;
    float4 acc[4];
#pragma unroll
    for (int i = 0; i < 4; ++i) acc[i] = make_float4(0.f, 0.f, 0.f, 0.f);

    int arow = tid >> 2;         // 0..63
    int akk  = (tid & 3) * 8;    // 0,8,16,24
    int am = m0 + arow; if (am > NN - 1) am = NN - 1;   // clamp: values unused for OOB rows
    int brow = tid >> 3;         // kk 0..31
    int bcol = (tid & 7) * 8;    // 0..56

    for (int k0 = 0; k0 < NF; k0 += 32) {
        float4 a0 = *(const float4*)(x + (size_t)am * NF + k0 + akk);
        float4 a1 = *(const float4*)(x + (size_t)am * NF + k0 + akk + 4);
        As[akk + 0][arow] = a0.x; As[akk + 1][arow] = a0.y;
        As[akk + 2][arow] = a0.z; As[akk + 3][arow] = a0.w;
        As[akk + 4][arow] = a1.x; As[akk + 5][arow] = a1.y;
        As[akk + 6][arow] = a1.z; As[akk + 7][arow] = a1.w;
        float4 b0 = *(const float4*)(Bsrc + (size_t)(k0 + brow) * NH + bcol);
        float4 b1 = *(const float4*)(Bsrc + (size_t)(k0 + brow) * NH + bcol + 4);
        *(float4*)&Bs[brow][bcol]     = b0;
        *(float4*)&Bs[brow][bcol + 4] = b1;
        __syncthreads();
#pragma unroll
        for (int kk = 0; kk < 32; ++kk) {
            float4 av = *(float4*)&As[kk][tm * 4];
            float4 bv = *(float4*)&Bs[kk][tn * 4];
            acc[0].x = fmaf(av.x, bv.x, acc[0].x); acc[0].y = fmaf(av.x, bv.y, acc[0].y);
            acc[0].z = fmaf(av.x, bv.z, acc[0].z); acc[0].w = fmaf(av.x, bv.w, acc[0].w);
            acc[1].x = fmaf(av.y, bv.x, acc[1].x); acc[1].y = fmaf(av.y, bv.y, acc[1].y);
            acc[1].z = fmaf(av.y, bv.z, acc[1].z); acc[1].w = fmaf(av.y, bv.w, acc[1].w);
            acc[2].x = fmaf(av.z, bv.x, acc[2].x); acc[2].y = fmaf(av.z, bv.y, acc[2].y);
            acc[2].z = fmaf(av.z, bv.z, acc[2].z); acc[2].w = fmaf(av.z, bv.w, acc[2].w);
            acc[3].x = fmaf(av.w, bv.x, acc[3].x); acc[3].y = fmaf(av.w, bv.y, acc[3].y);
            acc[3].z = fmaf(av.w, bv.z, acc[3].z); acc[3].w = fmaf(av.w, bv.w, acc[3].w);
        }
        __syncthreads();
    }
#pragma unroll
    for (int i = 0; i < 4; ++i) {
        int m = m0 + tm * 4 + i;
        if (m < NN) *(float4*)(h + (size_t)m * NF + n0 + tn * 4) = acc[i];
    }
}

// ---------------------------------------------------------------------------
// K4: edge pass 1. One wave per edge: softmax over 4 factor logits, top-2
// selection (ties -> lower index, matching lax.top_k), scatter e*h[dst] into
// hp[src] for the 2 active factors, att_loss partial sum.
__global__ __launch_bounds__(256) void edge_pass1(
        const int* __restrict__ edge,
        const float* __restrict__ s_src, const float* __restrict__ s_dst,
        const float* __restrict__ s1a, const float* __restrict__ s2a,
        const float* __restrict__ h, float* __restrict__ hp,
        float* __restrict__ rowsum, double* __restrict__ att_acc) {
    __shared__ float bsum;
    int tid = threadIdx.x;
    if (tid == 0) bsum = 0.f;
    __syncthreads();
    int lane = tid & 63;
    int e = blockIdx.x * 4 + (tid >> 6);
    if (e < NE) {
        int src = edge[e];
        int dst = edge[NE + e];
        float l0 = s_src[src * 4 + 0] + s_dst[dst * 4 + 0];
        float l1 = s_src[src * 4 + 1] + s_dst[dst * 4 + 1];
        float l2 = s_src[src * 4 + 2] + s_dst[dst * 4 + 2];
        float l3 = s_src[src * 4 + 3] + s_dst[dst * 4 + 3];
        int i1 = 0; float v1 = l0;
        if (l1 > v1) { v1 = l1; i1 = 1; }
        if (l2 > v1) { v1 = l2; i1 = 2; }
        if (l3 > v1) { v1 = l3; i1 = 3; }
        int i2 = 0; float v2 = -3.4e38f;
        if (i1 != 0)            { v2 = l0; i2 = 0; }
        if (i1 != 1 && l1 > v2) { v2 = l1; i2 = 1; }
        if (i1 != 2 && l2 > v2) { v2 = l2; i2 = 2; }
        if (i1 != 3 && l3 > v2) { v2 = l3; i2 = 3; }
        float esum = expf(l0 - v1) + expf(l1 - v1) + expf(l2 - v1) + expf(l3 - v1);
        float t2 = (1.f + expf(v2 - v1)) / esum;   // top-2 attention mass
        if (lane == 0) atomicAdd(&bsum, t2);
#pragma unroll
        for (int s = 0; s < 2; ++s) {
            int kf = s ? i2 : i1;
            float sv = s1a[src * 4 + kf] + s2a[dst * 4 + kf];
            float lr = sv >= 0.f ? sv : LRELU_ALPHA * sv;
            float ee = expf(-lr);
            if (lane == 0) atomicAdd(&rowsum[src * 4 + kf], ee);
            const float* hrow = h  + (size_t)dst * NF + kf * NH;
            float*      hprow = hp + (size_t)src * NF + kf * NH;
            atomicAdd(&hprow[lane],      ee * hrow[lane]);
            atomicAdd(&hprow[lane + 64], ee * hrow[lane + 64]);
        }
    }
    __syncthreads();
    if (tid == 0) atomicAdd(att_acc, (double)bsum);
}

// ---------------------------------------------------------------------------
// K5: node pass. out_cat = elu(hp/(rowsum+eps)); xo0 = out_cat @ W_o;
// s1o/s2o = xo0 . a_out halves. One wave per node (lane = class).
__global__ __launch_bounds__(256) void node_pass(
        const float* __restrict__ hp, const float* __restrict__ rowsum,
        const float* __restrict__ Wo, const float* __restrict__ a_out,
        float* __restrict__ xo0, float* __restrict__ s1o, float* __restrict__ s2o) {
    __shared__ float elurow[4][512];
    int tid = threadIdx.x;
    int w = tid >> 6, lane = tid & 63;
    int n = blockIdx.x * 4 + w;
    int nn = n < NN ? n : NN - 1;
    const float* hpr = hp + (size_t)nn * NF;
    float rs = rowsum[nn * 4 + (lane >> 4)] + EPSF;   // lane*8 .. lane*8+7 same factor
    float4 h0 = *(const float4*)(hpr + lane * 8);
    float4 h1 = *(const float4*)(hpr + lane * 8 + 4);
    float v[8] = {h0.x, h0.y, h0.z, h0.w, h1.x, h1.y, h1.z, h1.w};
#pragma unroll
    for (int i = 0; i < 8; ++i) {
        float t = v[i] / rs;
        v[i] = t > 0.f ? t : expm1f(t);
    }
    *(float4*)&elurow[w][lane * 8]     = make_float4(v[0], v[1], v[2], v[3]);
    *(float4*)&elurow[w][lane * 8 + 4] = make_float4(v[4], v[5], v[6], v[7]);
    __syncthreads();
    const float* er = elurow[w];
    float acc = 0.f;
#pragma unroll 8
    for (int j = 0; j < 512; ++j) acc = fmaf(er[j], Wo[j * 64 + lane], acc);
    float p1 = acc * a_out[lane];
    float p2 = acc * a_out[64 + lane];
#pragma unroll
    for (int off = 32; off >= 1; off >>= 1) {
        p1 += __shfl_xor(p1, off);
        p2 += __shfl_xor(p2, off);
    }
    if (n < NN) {
        xo0[(size_t)n * NC + lane] = acc;
        if (lane == 0) { s1o[n] = p1; s2o[n] = p2; }
    }
}

// ---------------------------------------------------------------------------
// K6: edge pass 2 (final attention layer, mask=None, F=64). One wave per edge.
__global__ __launch_bounds__(256) void edge_pass2(
        const int* __restrict__ edge,
        const float* __restrict__ s1o, const float* __restrict__ s2o,
        const float* __restrict__ xo0, float* __restrict__ hp2,
        float* __restrict__ rs2) {
    int tid = threadIdx.x;
    int lane = tid & 63;
    int e = blockIdx.x * 4 + (tid >> 6);
    if (e >= NE) return;
    int src = edge[e];
    int dst = edge[NE + e];
    float sv = s1o[src] + s2o[dst];
    float lr = sv >= 0.f ? sv : LRELU_ALPHA * sv;
    float ee = expf(-lr);
    if (lane == 0) atomicAdd(&rs2[src], ee);
    atomicAdd(&hp2[(size_t)src * NC + lane], ee * xo0[(size_t)dst * NC + lane]);
}

// ---------------------------------------------------------------------------
// K7: final: elu(hp2/(rs2+eps)) then log_softmax over 64 classes.
__global__ __launch_bounds__(256) void final_pass(
        const float* __restrict__ hp2, const float* __restrict__ rs2,
        float* __restrict__ out) {
    int tid = threadIdx.x;
    int w = tid >> 6, lane = tid & 63;
    int n = blockIdx.x * 4 + w;
    if (n >= NN) return;
    float t = hp2[(size_t)n * NC + lane] / (rs2[n] + EPSF);
    float v = t > 0.f ? t : expm1f(t);
    float m = v;
#pragma unroll
    for (int off = 32; off >= 1; off >>= 1) m = fmaxf(m, __shfl_xor(m, off));
    float p = expf(v - m);
#pragma unroll
    for (int off = 32; off >= 1; off >>= 1) p += __shfl_xor(p, off);
    out[(size_t)n * NC + lane] = v - m - logf(p);
}

__global__ void finalize_att(const double* __restrict__ att_acc, float* __restrict__ out) {
    out[(size_t)NN * NC] = 1.f - (float)(att_acc[0] / (double)NE);
}

// ---------------------------------------------------------------------------
extern "C" void kernel_launch(void* const* d_in, const int* in_sizes, int n_in,
                              void* d_out, int out_size, void* d_ws, size_t ws_size,
                              hipStream_t stream) {
    const float* x     = (const float*)d_in[0];
    const int*   edge  = (const int*)d_in[1];
    const float* Wks   = (const float*)d_in[2];
    const float* a_k   = (const float*)d_in[3];
    const float* Wo    = (const float*)d_in[4];
    const float* a_att = (const float*)d_in[5];
    const float* a_out = (const float*)d_in[6];
    float* out = (float*)d_out;

    float* wsf = (float*)d_ws;
    float* h      = wsf + OFF_H;
    float* P_T    = wsf + OFF_PT;
    float* s_src  = wsf + OFF_SSRC;
    float* s_dst  = wsf + OFF_SDST;
    float* s1a    = wsf + OFF_S1A;
    float* s2a    = wsf + OFF_S2A;
    float* xo0    = wsf + OFF_XO0;
    float* s1o    = wsf + OFF_S1O;
    float* s2o    = wsf + OFF_S2O;
    float* hp     = wsf + OFF_HP;
    float* rowsum = wsf + OFF_ROWSUM;
    float* hp2    = wsf + OFF_HP2;
    float* rs2    = wsf + OFF_RS2;
    double* att   = (double*)(wsf + OFF_ATT);

    // zero the accumulation region (hp, rowsum, hp2, rs2, att) every call
    size_t zero_bytes = (size_t)(WS_FLOATS - OFF_HP) * sizeof(float);
    hipMemsetAsync((char*)d_ws + (size_t)OFF_HP * sizeof(float), 0, zero_bytes, stream);

    precompute_P<<<1, 512, 0, stream>>>(Wks, a_k, a_att, P_T);
    compute_svals<<<(NN + 3) / 4, 256, 0, stream>>>(x, P_T, s_src, s_dst, s1a, s2a);
    gemm_h<<<dim3(NF / 64, (NN + 63) / 64), 256, 0, stream>>>(x, Wks, h);
    edge_pass1<<<(NE + 3) / 4, 256, 0, stream>>>(edge, s_src, s_dst, s1a, s2a, h, hp,
                                                 rowsum, att);
    node_pass<<<(NN + 3) / 4, 256, 0, stream>>>(hp, rowsum, Wo, a_out, xo0, s1o, s2o);
    edge_pass2<<<(NE + 3) / 4, 256, 0, stream>>>(edge, s1o, s2o, xo0, hp2, rs2);
    final_pass<<<(NN + 3) / 4, 256, 0, stream>>>(hp2, rs2, out);
    finalize_att<<<1, 1, 0, stream>>>(att, out);
}

// Round 2
// 1553.053 us; speedup vs baseline: 2.6220x; 2.6220x over previous
//
#include <hip/hip_runtime.h>
#include <math.h>

#define NN 50000
#define NE 800000
#define NF 512
#define NH 128
#define KF 4
#define NC 64
#define LRELU_ALPHA 0.2f
#define EPSF 1e-16f

// ---------------- workspace layout (float offsets) ----------------
#define OFF_H      0LL                                  // h (NN, 512) f32
#define OFF_SSRC   (OFF_H + (long long)NN * NF)         // (NN,4)
#define OFF_SDST   (OFF_SSRC + (long long)NN * KF)
#define OFF_S1A    (OFF_SDST + (long long)NN * KF)
#define OFF_S2A    (OFF_S1A + (long long)NN * KF)
#define OFF_XO0    (OFF_S2A + (long long)NN * KF)       // (NN,64)
#define OFF_S1O    (OFF_XO0 + (long long)NN * NC)
#define OFF_S2O    (OFF_S1O + NN)
#define OFF_HP     (OFF_S2O + NN)                       // (NN,512)
#define OFF_ROWSUM (OFF_HP + (long long)NN * NF)        // (NN,4)
#define OFF_START  (OFF_ROWSUM + (long long)NN * KF)    // (NN+2) ints (padded even)
#define OFF_EIDX   (OFF_START + NN + 2)                 // NE ints
// ---- zeroed-each-call region starts here ----
#define OFF_CNT    (OFF_EIDX + (long long)NE)           // NN ints
#define OFF_CURSOR (OFF_CNT + NN)                       // NN ints
#define OFF_ATT    (OFF_CURSOR + NN)                    // double (2 floats), 8B-aligned
#define WS_FLOATS  (OFF_ATT + 2)

// ---------------------------------------------------------------------------
// K1: h = x @ Wcat (f32). Wcat[f][k*128+j] = Wks[k][f][j]. 64x64 tile, BK=32,
// 256 threads, 4x4 microtile. No fp32 MFMA on CDNA4 -> vector ALU GEMM.
__global__ __launch_bounds__(256) void gemm_h(const float* __restrict__ x,
                                              const float* __restrict__ Wks,
                                              float* __restrict__ h) {
    __shared__ float As[32][64];
    __shared__ float Bs[32][64];
    int m0 = blockIdx.y * 64;
    int n0 = blockIdx.x * 64;
    int kf = n0 >> 7, jb = n0 & 127;
    const float* Bsrc = Wks + (size_t)kf * (NF * NH) + jb;
    int tid = threadIdx.x;
    int tm = tid >> 4, tn = tid & 15;
    float4 acc[4];
#pragma unroll
    for (int i = 0; i < 4; ++i) acc[i] = make_float4(0.f, 0.f, 0.f, 0.f);

    int arow = tid >> 2;         // 0..63
    int akk  = (tid & 3) * 8;    // 0,8,16,24
    int am = m0 + arow; if (am > NN - 1) am = NN - 1;   // clamp: values unused for OOB rows
    int brow = tid >> 3;         // kk 0..31
    int bcol = (tid & 7) * 8;    // 0..56

    for (int k0 = 0; k0 < NF; k0 += 32) {
        float4 a0 = *(const float4*)(x + (size_t)am * NF + k0 + akk);
        float4 a1 = *(const float4*)(x + (size_t)am * NF + k0 + akk + 4);
        As[akk + 0][arow] = a0.x; As[akk + 1][arow] = a0.y;
        As[akk + 2][arow] = a0.z; As[akk + 3][arow] = a0.w;
        As[akk + 4][arow] = a1.x; As[akk + 5][arow] = a1.y;
        As[akk + 6][arow] = a1.z; As[akk + 7][arow] = a1.w;
        float4 b0 = *(const float4*)(Bsrc + (size_t)(k0 + brow) * NH + bcol);
        float4 b1 = *(const float4*)(Bsrc + (size_t)(k0 + brow) * NH + bcol + 4);
        *(float4*)&Bs[brow][bcol]     = b0;
        *(float4*)&Bs[brow][bcol + 4] = b1;
        __syncthreads();
#pragma unroll
        for (int kk = 0; kk < 32; ++kk) {
            float4 av = *(float4*)&As[kk][tm * 4];
            float4 bv = *(float4*)&Bs[kk][tn * 4];
            acc[0].x = fmaf(av.x, bv.x, acc[0].x); acc[0].y = fmaf(av.x, bv.y, acc[0].y);
            acc[0].z = fmaf(av.x, bv.z, acc[0].z); acc[0].w = fmaf(av.x, bv.w, acc[0].w);
            acc[1].x = fmaf(av.y, bv.x, acc[1].x); acc[1].y = fmaf(av.y, bv.y, acc[1].y);
            acc[1].z = fmaf(av.y, bv.z, acc[1].z); acc[1].w = fmaf(av.y, bv.w, acc[1].w);
            acc[2].x = fmaf(av.z, bv.x, acc[2].x); acc[2].y = fmaf(av.z, bv.y, acc[2].y);
            acc[2].z = fmaf(av.z, bv.z, acc[2].z); acc[2].w = fmaf(av.z, bv.w, acc[2].w);
            acc[3].x = fmaf(av.w, bv.x, acc[3].x); acc[3].y = fmaf(av.w, bv.y, acc[3].y);
            acc[3].z = fmaf(av.w, bv.z, acc[3].z); acc[3].w = fmaf(av.w, bv.w, acc[3].w);
        }
        __syncthreads();
    }
#pragma unroll
    for (int i = 0; i < 4; ++i) {
        int m = m0 + tm * 4 + i;
        if (m < NN) *(float4*)(h + (size_t)m * NF + n0 + tn * 4) = acc[i];
    }
}

// ---------------------------------------------------------------------------
// K2: routing/attention scalars from h (matches reference contraction h @ a).
// One wave per node; a_k (16KB) and a_att (4KB) staged in LDS.
__global__ __launch_bounds__(256) void compute_svals_h(
        const float* __restrict__ h, const float* __restrict__ a_k,
        const float* __restrict__ a_att,
        float* __restrict__ s_src, float* __restrict__ s_dst,
        float* __restrict__ s1a, float* __restrict__ s2a) {
    __shared__ float Ak[4][1024];
    __shared__ float Aa[4][256];
    for (int i = threadIdx.x; i < 4096; i += 256) Ak[i >> 10][i & 1023] = a_k[i];
    for (int i = threadIdx.x; i < 1024; i += 256) Aa[i >> 8][i & 255] = a_att[i];
    __syncthreads();
    int w = threadIdx.x >> 6, lane = threadIdx.x & 63;
    int n = blockIdx.x * 4 + w;
    if (n >= NN) return;
    const float* hr = h + (size_t)n * NF;
    float accS[4] = {0, 0, 0, 0}, accD[4] = {0, 0, 0, 0};
    float accQ1[4] = {0, 0, 0, 0}, accQ2[4] = {0, 0, 0, 0};
#pragma unroll
    for (int i = 0; i < 8; ++i) {
        int f = i * 64 + lane;
        float hv = hr[f];
#pragma unroll
        for (int k = 0; k < 4; ++k) {
            accS[k] = fmaf(hv, Ak[k][f], accS[k]);
            accD[k] = fmaf(hv, Ak[k][512 + f], accD[k]);
        }
        accQ1[i >> 1] = fmaf(hv, Aa[i >> 1][f & 127], accQ1[i >> 1]);
        accQ2[i >> 1] = fmaf(hv, Aa[i >> 1][128 + (f & 127)], accQ2[i >> 1]);
    }
#pragma unroll
    for (int off = 32; off >= 1; off >>= 1) {
#pragma unroll
        for (int k = 0; k < 4; ++k) {
            accS[k] += __shfl_xor(accS[k], off);
            accD[k] += __shfl_xor(accD[k], off);
            accQ1[k] += __shfl_xor(accQ1[k], off);
            accQ2[k] += __shfl_xor(accQ2[k], off);
        }
    }
    if (lane == 0) {
#pragma unroll
        for (int k = 0; k < 4; ++k) {
            s_src[n * 4 + k] = accS[k];
            s_dst[n * 4 + k] = accD[k];
            s1a[n * 4 + k]   = accQ1[k];
            s2a[n * 4 + k]   = accQ2[k];
        }
    }
}

// ---------------------------------------------------------------------------
// CSR build: count / scan / fill  (src -> incoming edge list)
__global__ void csr_count(const int* __restrict__ edge, int* __restrict__ cnt) {
    int e = blockIdx.x * 256 + threadIdx.x;
    if (e < NE) atomicAdd(&cnt[edge[e]], 1);
}

__global__ __launch_bounds__(1024) void csr_scan(const int* __restrict__ cnt,
                                                 int* __restrict__ start) {
    __shared__ int part[1024];
    int t = threadIdx.x;
    const int CH = (NN + 1023) / 1024;  // 49
    int base = t * CH;
    int s = 0;
    for (int i = 0; i < CH; ++i) {
        int idx = base + i;
        if (idx < NN) s += cnt[idx];
    }
    part[t] = s;
    __syncthreads();
    for (int off = 1; off < 1024; off <<= 1) {
        int v = (t >= off) ? part[t - off] : 0;
        __syncthreads();
        part[t] += v;
        __syncthreads();
    }
    int run = (t == 0) ? 0 : part[t - 1];
    for (int i = 0; i < CH; ++i) {
        int idx = base + i;
        if (idx < NN) { start[idx] = run; run += cnt[idx]; }
    }
    if (t == 1023) start[NN] = run;
}

__global__ void csr_fill(const int* __restrict__ edge, const int* __restrict__ start,
                         int* __restrict__ cursor, int* __restrict__ eidx) {
    int e = blockIdx.x * 256 + threadIdx.x;
    if (e >= NE) return;
    int s = edge[e];
    int r = atomicAdd(&cursor[s], 1);
    eidx[start[s] + r] = e;
}

// ---------------------------------------------------------------------------
// K3: layer-1 gather. One wave per node: loop incoming edges, per-edge softmax
// over 4 factor logits + top-2 (ties -> lower index, matching lax.top_k),
// accumulate ee*h[dst] for the 2 active factors in registers. No atomics on
// feature data.
__global__ __launch_bounds__(256) void node_gather1(
        const int* __restrict__ edge, const int* __restrict__ start,
        const int* __restrict__ eidx,
        const float* __restrict__ s_src, const float* __restrict__ s_dst,
        const float* __restrict__ s1a, const float* __restrict__ s2a,
        const float* __restrict__ h, float* __restrict__ hp,
        float* __restrict__ rowsum, double* __restrict__ att_acc) {
    int w = threadIdx.x >> 6, lane = threadIdx.x & 63;
    int n = blockIdx.x * 4 + w;
    if (n >= NN) return;
    int j0 = start[n], j1 = start[n + 1];
    float4 ss = *(const float4*)(s_src + (size_t)n * 4);
    float4 q1 = *(const float4*)(s1a + (size_t)n * 4);
    float acc[8] = {0, 0, 0, 0, 0, 0, 0, 0};
    float rs0 = 0.f, rs1 = 0.f, rs2 = 0.f, rs3 = 0.f;
    float attsum = 0.f;
    for (int j = j0; j < j1; ++j) {
        int e = eidx[j];
        int dst = edge[NE + e];
        float4 sd = *(const float4*)(s_dst + (size_t)dst * 4);
        float l0 = ss.x + sd.x, l1 = ss.y + sd.y, l2 = ss.z + sd.z, l3 = ss.w + sd.w;
        int i1 = 0; float v1 = l0;
        if (l1 > v1) { v1 = l1; i1 = 1; }
        if (l2 > v1) { v1 = l2; i1 = 2; }
        if (l3 > v1) { v1 = l3; i1 = 3; }
        int i2 = 0; float v2 = -3.4e38f;
        if (i1 != 0)            { v2 = l0; i2 = 0; }
        if (i1 != 1 && l1 > v2) { v2 = l1; i2 = 1; }
        if (i1 != 2 && l2 > v2) { v2 = l2; i2 = 2; }
        if (i1 != 3 && l3 > v2) { v2 = l3; i2 = 3; }
        float esum = expf(l0 - v1) + expf(l1 - v1) + expf(l2 - v1) + expf(l3 - v1);
        attsum += (1.f + expf(v2 - v1)) / esum;
        float4 q2 = *(const float4*)(s2a + (size_t)dst * 4);
        const float* hrow = h + (size_t)dst * NF;
#pragma unroll
        for (int s = 0; s < 2; ++s) {
            int kf = s ? i2 : i1;
            float q1v = kf == 0 ? q1.x : kf == 1 ? q1.y : kf == 2 ? q1.z : q1.w;
            float q2v = kf == 0 ? q2.x : kf == 1 ? q2.y : kf == 2 ? q2.z : q2.w;
            float sv = q1v + q2v;
            float ee = expf(-(sv >= 0.f ? sv : LRELU_ALPHA * sv));
            switch (kf) {  // kf is wave-uniform -> scalar branch, static acc index
                case 0: rs0 += ee;
                        acc[0] = fmaf(ee, hrow[lane],       acc[0]);
                        acc[1] = fmaf(ee, hrow[64 + lane],  acc[1]); break;
                case 1: rs1 += ee;
                        acc[2] = fmaf(ee, hrow[128 + lane], acc[2]);
                        acc[3] = fmaf(ee, hrow[192 + lane], acc[3]); break;
                case 2: rs2 += ee;
                        acc[4] = fmaf(ee, hrow[256 + lane], acc[4]);
                        acc[5] = fmaf(ee, hrow[320 + lane], acc[5]); break;
                default: rs3 += ee;
                        acc[6] = fmaf(ee, hrow[384 + lane], acc[6]);
                        acc[7] = fmaf(ee, hrow[448 + lane], acc[7]); break;
            }
        }
    }
    float* hpr = hp + (size_t)n * NF;
#pragma unroll
    for (int t = 0; t < 8; ++t) hpr[t * 64 + lane] = acc[t];
    if (lane == 0) {
        rowsum[n * 4 + 0] = rs0;
        rowsum[n * 4 + 1] = rs1;
        rowsum[n * 4 + 2] = rs2;
        rowsum[n * 4 + 3] = rs3;
        atomicAdd(att_acc, (double)attsum);
    }
}

// ---------------------------------------------------------------------------
// K4: node pass. out_cat = elu(hp/(rowsum+eps)); xo0 = out_cat @ W_o;
// s1o/s2o = xo0 . a_out halves. One wave per node (lane = class).
__global__ __launch_bounds__(256) void node_pass(
        const float* __restrict__ hp, const float* __restrict__ rowsum,
        const float* __restrict__ Wo, const float* __restrict__ a_out,
        float* __restrict__ xo0, float* __restrict__ s1o, float* __restrict__ s2o) {
    __shared__ float elurow[4][512];
    int tid = threadIdx.x;
    int w = tid >> 6, lane = tid & 63;
    int n = blockIdx.x * 4 + w;
    int nn = n < NN ? n : NN - 1;
    const float* hpr = hp + (size_t)nn * NF;
    float rs = rowsum[nn * 4 + (lane >> 4)] + EPSF;   // lane*8..lane*8+7 same factor
    float4 h0 = *(const float4*)(hpr + lane * 8);
    float4 h1 = *(const float4*)(hpr + lane * 8 + 4);
    float v[8] = {h0.x, h0.y, h0.z, h0.w, h1.x, h1.y, h1.z, h1.w};
#pragma unroll
    for (int i = 0; i < 8; ++i) {
        float t = v[i] / rs;
        v[i] = t > 0.f ? t : expm1f(t);
    }
    *(float4*)&elurow[w][lane * 8]     = make_float4(v[0], v[1], v[2], v[3]);
    *(float4*)&elurow[w][lane * 8 + 4] = make_float4(v[4], v[5], v[6], v[7]);
    __syncthreads();
    const float* er = elurow[w];
    float acc = 0.f;
#pragma unroll 8
    for (int j = 0; j < 512; ++j) acc = fmaf(er[j], Wo[j * 64 + lane], acc);
    float p1 = acc * a_out[lane];
    float p2 = acc * a_out[64 + lane];
#pragma unroll
    for (int off = 32; off >= 1; off >>= 1) {
        p1 += __shfl_xor(p1, off);
        p2 += __shfl_xor(p2, off);
    }
    if (n < NN) {
        xo0[(size_t)n * NC + lane] = acc;
        if (lane == 0) { s1o[n] = p1; s2o[n] = p2; }
    }
}

// ---------------------------------------------------------------------------
// K5: output attention layer fused with elu + log-softmax. One wave per node.
__global__ __launch_bounds__(256) void node_gather2(
        const int* __restrict__ edge, const int* __restrict__ start,
        const int* __restrict__ eidx,
        const float* __restrict__ s1o, const float* __restrict__ s2o,
        const float* __restrict__ xo0, float* __restrict__ out) {
    int w = threadIdx.x >> 6, lane = threadIdx.x & 63;
    int n = blockIdx.x * 4 + w;
    if (n >= NN) return;
    int j0 = start[n], j1 = start[n + 1];
    float sn = s1o[n];
    float acc = 0.f, rsum = 0.f;
    for (int j = j0; j < j1; ++j) {
        int e = eidx[j];
        int dst = edge[NE + e];
        float sv = sn + s2o[dst];
        float ee = expf(-(sv >= 0.f ? sv : LRELU_ALPHA * sv));
        rsum += ee;
        acc = fmaf(ee, xo0[(size_t)dst * NC + lane], acc);
    }
    float t = acc / (rsum + EPSF);
    float v = t > 0.f ? t : expm1f(t);
    float m = v;
#pragma unroll
    for (int off = 32; off >= 1; off >>= 1) m = fmaxf(m, __shfl_xor(m, off));
    float p = expf(v - m);
#pragma unroll
    for (int off = 32; off >= 1; off >>= 1) p += __shfl_xor(p, off);
    out[(size_t)n * NC + lane] = v - m - logf(p);
}

__global__ void finalize_att(const double* __restrict__ att_acc, float* __restrict__ out) {
    out[(size_t)NN * NC] = 1.f - (float)(att_acc[0] / (double)NE);
}

// ---------------------------------------------------------------------------
extern "C" void kernel_launch(void* const* d_in, const int* in_sizes, int n_in,
                              void* d_out, int out_size, void* d_ws, size_t ws_size,
                              hipStream_t stream) {
    const float* x     = (const float*)d_in[0];
    const int*   edge  = (const int*)d_in[1];
    const float* Wks   = (const float*)d_in[2];
    const float* a_k   = (const float*)d_in[3];
    const float* Wo    = (const float*)d_in[4];
    const float* a_att = (const float*)d_in[5];
    const float* a_out = (const float*)d_in[6];
    float* out = (float*)d_out;

    float* wsf = (float*)d_ws;
    float* h      = wsf + OFF_H;
    float* s_src  = wsf + OFF_SSRC;
    float* s_dst  = wsf + OFF_SDST;
    float* s1a    = wsf + OFF_S1A;
    float* s2a    = wsf + OFF_S2A;
    float* xo0    = wsf + OFF_XO0;
    float* s1o    = wsf + OFF_S1O;
    float* s2o    = wsf + OFF_S2O;
    float* hp     = wsf + OFF_HP;
    float* rowsum = wsf + OFF_ROWSUM;
    int*   startp = (int*)(wsf + OFF_START);
    int*   eidx   = (int*)(wsf + OFF_EIDX);
    int*   cnt    = (int*)(wsf + OFF_CNT);
    int*   cursor = (int*)(wsf + OFF_CURSOR);
    double* att   = (double*)(wsf + OFF_ATT);

    // zero only the small accumulation region (cnt, cursor, att) every call
    size_t zero_bytes = (size_t)(WS_FLOATS - OFF_CNT) * sizeof(float);
    hipMemsetAsync((char*)d_ws + (size_t)OFF_CNT * sizeof(float), 0, zero_bytes, stream);

    gemm_h<<<dim3(NF / 64, (NN + 63) / 64), 256, 0, stream>>>(x, Wks, h);
    compute_svals_h<<<(NN + 3) / 4, 256, 0, stream>>>(h, a_k, a_att,
                                                      s_src, s_dst, s1a, s2a);
    csr_count<<<(NE + 255) / 256, 256, 0, stream>>>(edge, cnt);
    csr_scan<<<1, 1024, 0, stream>>>(cnt, startp);
    csr_fill<<<(NE + 255) / 256, 256, 0, stream>>>(edge, startp, cursor, eidx);
    node_gather1<<<(NN + 3) / 4, 256, 0, stream>>>(edge, startp, eidx, s_src, s_dst,
                                                   s1a, s2a, h, hp, rowsum, att);
    node_pass<<<(NN + 3) / 4, 256, 0, stream>>>(hp, rowsum, Wo, a_out, xo0, s1o, s2o);
    node_gather2<<<(NN + 3) / 4, 256, 0, stream>>>(edge, startp, eidx, s1o, s2o,
                                                   xo0, out);
    finalize_att<<<1, 1, 0, stream>>>(att, out);
}

// Round 3
// 1022.155 us; speedup vs baseline: 3.9839x; 1.5194x over previous
//
#include <hip/hip_runtime.h>
#include <math.h>

#define NN 50000
#define NE 800000
#define NF 512
#define NH 128
#define KF 4
#define NC 64
#define LRELU_ALPHA 0.2f
#define EPSF 1e-16f

// ---------------- workspace layout (float offsets) ----------------
#define OFF_H      0LL                                  // h (NN,512)
#define OFF_HP     (OFF_H + (long long)NN * NF)         // hp (NN,512)
#define OFF_REC    (OFF_HP + (long long)NN * NF)        // rec (NE int4) 16B aligned
#define OFF_XO0    (OFF_REC + 4LL * NE)                 // (NN,64)
#define OFF_EEO    (OFF_XO0 + (long long)NN * NC)       // (NE,)
#define OFF_SSRC   (OFF_EEO + (long long)NE)            // (NN,4)
#define OFF_SDST   (OFF_SSRC + (long long)NN * KF)
#define OFF_S1A    (OFF_SDST + (long long)NN * KF)
#define OFF_S2A    (OFF_S1A + (long long)NN * KF)
#define OFF_ROWSUM (OFF_S2A + (long long)NN * KF)       // (NN,4)
#define OFF_S1O    (OFF_ROWSUM + (long long)NN * KF)    // (NN,)
#define OFF_S2O    (OFF_S1O + NN)
#define OFF_START  (OFF_S2O + NN)                       // (NN+1) ints, pad to even+2
// ---- zeroed-each-call region starts here ----
#define OFF_CNT    (OFF_START + NN + 4)                 // NN ints
#define OFF_CURSOR (OFF_CNT + NN)                       // NN ints
#define OFF_ATT    (OFF_CURSOR + NN)                    // double (2 floats), 8B-aligned
#define WS_FLOATS  (OFF_ATT + 2)

// ---------------------------------------------------------------------------
// K1: h = x @ Wcat (f32). Wcat[f][k*128+j] = Wks[k][f][j]. 64x64 tile, BK=32,
// 256 threads, 4x4 microtile. No fp32 MFMA on CDNA4 -> vector ALU GEMM.
__global__ __launch_bounds__(256) void gemm_h(const float* __restrict__ x,
                                              const float* __restrict__ Wks,
                                              float* __restrict__ h) {
    __shared__ float As[32][64];
    __shared__ float Bs[32][64];
    int m0 = blockIdx.y * 64;
    int n0 = blockIdx.x * 64;
    int kf = n0 >> 7, jb = n0 & 127;
    const float* Bsrc = Wks + (size_t)kf * (NF * NH) + jb;
    int tid = threadIdx.x;
    int tm = tid >> 4, tn = tid & 15;
    float4 acc[4];
#pragma unroll
    for (int i = 0; i < 4; ++i) acc[i] = make_float4(0.f, 0.f, 0.f, 0.f);

    int arow = tid >> 2;         // 0..63
    int akk  = (tid & 3) * 8;    // 0,8,16,24
    int am = m0 + arow; if (am > NN - 1) am = NN - 1;   // clamp: values unused for OOB
    int brow = tid >> 3;         // kk 0..31
    int bcol = (tid & 7) * 8;    // 0..56

    for (int k0 = 0; k0 < NF; k0 += 32) {
        float4 a0 = *(const float4*)(x + (size_t)am * NF + k0 + akk);
        float4 a1 = *(const float4*)(x + (size_t)am * NF + k0 + akk + 4);
        As[akk + 0][arow] = a0.x; As[akk + 1][arow] = a0.y;
        As[akk + 2][arow] = a0.z; As[akk + 3][arow] = a0.w;
        As[akk + 4][arow] = a1.x; As[akk + 5][arow] = a1.y;
        As[akk + 6][arow] = a1.z; As[akk + 7][arow] = a1.w;
        float4 b0 = *(const float4*)(Bsrc + (size_t)(k0 + brow) * NH + bcol);
        float4 b1 = *(const float4*)(Bsrc + (size_t)(k0 + brow) * NH + bcol + 4);
        *(float4*)&Bs[brow][bcol]     = b0;
        *(float4*)&Bs[brow][bcol + 4] = b1;
        __syncthreads();
#pragma unroll
        for (int kk = 0; kk < 32; ++kk) {
            float4 av = *(float4*)&As[kk][tm * 4];
            float4 bv = *(float4*)&Bs[kk][tn * 4];
            acc[0].x = fmaf(av.x, bv.x, acc[0].x); acc[0].y = fmaf(av.x, bv.y, acc[0].y);
            acc[0].z = fmaf(av.x, bv.z, acc[0].z); acc[0].w = fmaf(av.x, bv.w, acc[0].w);
            acc[1].x = fmaf(av.y, bv.x, acc[1].x); acc[1].y = fmaf(av.y, bv.y, acc[1].y);
            acc[1].z = fmaf(av.y, bv.z, acc[1].z); acc[1].w = fmaf(av.y, bv.w, acc[1].w);
            acc[2].x = fmaf(av.z, bv.x, acc[2].x); acc[2].y = fmaf(av.z, bv.y, acc[2].y);
            acc[2].z = fmaf(av.z, bv.z, acc[2].z); acc[2].w = fmaf(av.z, bv.w, acc[2].w);
            acc[3].x = fmaf(av.w, bv.x, acc[3].x); acc[3].y = fmaf(av.w, bv.y, acc[3].y);
            acc[3].z = fmaf(av.w, bv.z, acc[3].z); acc[3].w = fmaf(av.w, bv.w, acc[3].w);
        }
        __syncthreads();
    }
#pragma unroll
    for (int i = 0; i < 4; ++i) {
        int m = m0 + tm * 4 + i;
        if (m < NN) *(float4*)(h + (size_t)m * NF + n0 + tn * 4) = acc[i];
    }
}

// ---------------------------------------------------------------------------
// K2: routing/attention scalars from h (matches reference contraction h @ a).
__global__ __launch_bounds__(256) void compute_svals_h(
        const float* __restrict__ h, const float* __restrict__ a_k,
        const float* __restrict__ a_att,
        float* __restrict__ s_src, float* __restrict__ s_dst,
        float* __restrict__ s1a, float* __restrict__ s2a) {
    __shared__ float Ak[4][1024];
    __shared__ float Aa[4][256];
    for (int i = threadIdx.x; i < 4096; i += 256) Ak[i >> 10][i & 1023] = a_k[i];
    for (int i = threadIdx.x; i < 1024; i += 256) Aa[i >> 8][i & 255] = a_att[i];
    __syncthreads();
    int w = threadIdx.x >> 6, lane = threadIdx.x & 63;
    int n = blockIdx.x * 4 + w;
    if (n >= NN) return;
    const float* hr = h + (size_t)n * NF;
    float accS[4] = {0, 0, 0, 0}, accD[4] = {0, 0, 0, 0};
    float accQ1[4] = {0, 0, 0, 0}, accQ2[4] = {0, 0, 0, 0};
#pragma unroll
    for (int i = 0; i < 8; ++i) {
        int f = i * 64 + lane;
        float hv = hr[f];
#pragma unroll
        for (int k = 0; k < 4; ++k) {
            accS[k] = fmaf(hv, Ak[k][f], accS[k]);
            accD[k] = fmaf(hv, Ak[k][512 + f], accD[k]);
        }
        accQ1[i >> 1] = fmaf(hv, Aa[i >> 1][f & 127], accQ1[i >> 1]);
        accQ2[i >> 1] = fmaf(hv, Aa[i >> 1][128 + (f & 127)], accQ2[i >> 1]);
    }
#pragma unroll
    for (int off = 32; off >= 1; off >>= 1) {
#pragma unroll
        for (int k = 0; k < 4; ++k) {
            accS[k] += __shfl_xor(accS[k], off);
            accD[k] += __shfl_xor(accD[k], off);
            accQ1[k] += __shfl_xor(accQ1[k], off);
            accQ2[k] += __shfl_xor(accQ2[k], off);
        }
    }
    if (lane == 0) {
#pragma unroll
        for (int k = 0; k < 4; ++k) {
            s_src[n * 4 + k] = accS[k];
            s_dst[n * 4 + k] = accD[k];
            s1a[n * 4 + k]   = accQ1[k];
            s2a[n * 4 + k]   = accQ2[k];
        }
    }
}

// ---------------------------------------------------------------------------
// CSR build: count / scan
__global__ void csr_count(const int* __restrict__ edge, int* __restrict__ cnt) {
    int e = blockIdx.x * 256 + threadIdx.x;
    if (e < NE) atomicAdd(&cnt[edge[e]], 1);
}

__global__ __launch_bounds__(1024) void csr_scan(const int* __restrict__ cnt,
                                                 int* __restrict__ start) {
    __shared__ int part[1024];
    int t = threadIdx.x;
    const int CH = (NN + 1023) / 1024;  // 49
    int base = t * CH;
    int s = 0;
    for (int i = 0; i < CH; ++i) {
        int idx = base + i;
        if (idx < NN) s += cnt[idx];
    }
    part[t] = s;
    __syncthreads();
    for (int off = 1; off < 1024; off <<= 1) {
        int v = (t >= off) ? part[t - off] : 0;
        __syncthreads();
        part[t] += v;
        __syncthreads();
    }
    int run = (t == 0) ? 0 : part[t - 1];
    for (int i = 0; i < CH; ++i) {
        int idx = base + i;
        if (idx < NN) { start[idx] = run; run += cnt[idx]; }
    }
    if (t == 1023) start[NN] = run;
}

// ---------------------------------------------------------------------------
// K3: edge-parallel scalar precompute + CSR fill. One thread per edge:
// softmax over 4 factor logits, top-2 (ties -> lower index, matching
// lax.top_k), both layer-1 e-values; writes a CSR-positioned 16B record
// {dst, src|kf1<<16|kf2<<18, ee1, ee2}. att_loss mass block-reduced.
__global__ __launch_bounds__(256) void edge_pre1(
        const int* __restrict__ edge, const int* __restrict__ start,
        int* __restrict__ cursor,
        const float* __restrict__ s_src, const float* __restrict__ s_dst,
        const float* __restrict__ s1a, const float* __restrict__ s2a,
        int4* __restrict__ rec, double* __restrict__ att_acc) {
    __shared__ float blk[4];
    int tid = threadIdx.x;
    int e = blockIdx.x * 256 + tid;
    float t2 = 0.f;
    if (e < NE) {
        int src = edge[e];
        int dst = edge[NE + e];
        float4 ss = *(const float4*)(s_src + (size_t)src * 4);
        float4 sd = *(const float4*)(s_dst + (size_t)dst * 4);
        float l0 = ss.x + sd.x, l1 = ss.y + sd.y, l2 = ss.z + sd.z, l3 = ss.w + sd.w;
        int i1 = 0; float v1 = l0;
        if (l1 > v1) { v1 = l1; i1 = 1; }
        if (l2 > v1) { v1 = l2; i1 = 2; }
        if (l3 > v1) { v1 = l3; i1 = 3; }
        int i2 = 0; float v2 = -3.4e38f;
        if (i1 != 0)            { v2 = l0; i2 = 0; }
        if (i1 != 1 && l1 > v2) { v2 = l1; i2 = 1; }
        if (i1 != 2 && l2 > v2) { v2 = l2; i2 = 2; }
        if (i1 != 3 && l3 > v2) { v2 = l3; i2 = 3; }
        float esum = expf(l0 - v1) + expf(l1 - v1) + expf(l2 - v1) + expf(l3 - v1);
        t2 = (1.f + expf(v2 - v1)) / esum;
        float4 q1 = *(const float4*)(s1a + (size_t)src * 4);
        float4 q2 = *(const float4*)(s2a + (size_t)dst * 4);
        float q1v1 = i1 == 0 ? q1.x : i1 == 1 ? q1.y : i1 == 2 ? q1.z : q1.w;
        float q2v1 = i1 == 0 ? q2.x : i1 == 1 ? q2.y : i1 == 2 ? q2.z : q2.w;
        float q1v2 = i2 == 0 ? q1.x : i2 == 1 ? q1.y : i2 == 2 ? q1.z : q1.w;
        float q2v2 = i2 == 0 ? q2.x : i2 == 1 ? q2.y : i2 == 2 ? q2.z : q2.w;
        float sv1 = q1v1 + q2v1, sv2 = q1v2 + q2v2;
        float ee1 = expf(-(sv1 >= 0.f ? sv1 : LRELU_ALPHA * sv1));
        float ee2 = expf(-(sv2 >= 0.f ? sv2 : LRELU_ALPHA * sv2));
        int p = start[src] + atomicAdd(&cursor[src], 1);
        rec[p] = make_int4(dst, src | (i1 << 16) | (i2 << 18),
                           __float_as_int(ee1), __float_as_int(ee2));
    }
#pragma unroll
    for (int off = 32; off >= 1; off >>= 1) t2 += __shfl_xor(t2, off);
    if ((tid & 63) == 0) blk[tid >> 6] = t2;
    __syncthreads();
    if (tid == 0)
        atomicAdd(att_acc, (double)(blk[0] + blk[1] + blk[2] + blk[3]));
}

// ---------------------------------------------------------------------------
// K4: layer-1 gather. One block per node, one wave per factor. Wave k scans
// the node's CSR records (wave-uniform 16B loads) and accumulates
// ee * h[dst, k*128 + {lane, 64+lane}] for edges whose top-2 contains k.
__global__ __launch_bounds__(256) void node_gather1(
        const int* __restrict__ start, const int4* __restrict__ rec,
        const float* __restrict__ h, float* __restrict__ hp,
        float* __restrict__ rowsum) {
    int n = blockIdx.x;
    int k = threadIdx.x >> 6;
    int lane = threadIdx.x & 63;
    int j0 = start[n], j1 = start[n + 1];
    const float* hbase = h + (size_t)k * NH + lane;
    float a0 = 0.f, a1 = 0.f, rs = 0.f;
    int j = j0;
    for (; j + 1 < j1; j += 2) {
        int4 ra = rec[j];
        int4 rb = rec[j + 1];
        int i1a = (ra.y >> 16) & 3, i2a = (ra.y >> 18) & 3;
        int i1b = (rb.y >> 16) & 3, i2b = (rb.y >> 18) & 3;
        float wa = (i1a == k) ? __int_as_float(ra.z)
                 : (i2a == k) ? __int_as_float(ra.w) : 0.f;
        float wb = (i1b == k) ? __int_as_float(rb.z)
                 : (i2b == k) ? __int_as_float(rb.w) : 0.f;
        if (wa != 0.f) {
            const float* hr = hbase + (size_t)ra.x * NF;
            a0 = fmaf(wa, hr[0], a0);
            a1 = fmaf(wa, hr[64], a1);
            rs += wa;
        }
        if (wb != 0.f) {
            const float* hr = hbase + (size_t)rb.x * NF;
            a0 = fmaf(wb, hr[0], a0);
            a1 = fmaf(wb, hr[64], a1);
            rs += wb;
        }
    }
    if (j < j1) {
        int4 ra = rec[j];
        int i1a = (ra.y >> 16) & 3, i2a = (ra.y >> 18) & 3;
        float wa = (i1a == k) ? __int_as_float(ra.z)
                 : (i2a == k) ? __int_as_float(ra.w) : 0.f;
        if (wa != 0.f) {
            const float* hr = hbase + (size_t)ra.x * NF;
            a0 = fmaf(wa, hr[0], a0);
            a1 = fmaf(wa, hr[64], a1);
            rs += wa;
        }
    }
    float* hpr = hp + (size_t)n * NF + k * NH;
    hpr[lane]      = a0;
    hpr[64 + lane] = a1;
    if (lane == 0) rowsum[n * 4 + k] = rs;
}

// ---------------------------------------------------------------------------
// K5: node pass. out_cat = elu(hp/(rowsum+eps)); xo0 = out_cat @ W_o;
// s1o/s2o = xo0 . a_out halves. One wave per node (lane = class).
__global__ __launch_bounds__(256) void node_pass(
        const float* __restrict__ hp, const float* __restrict__ rowsum,
        const float* __restrict__ Wo, const float* __restrict__ a_out,
        float* __restrict__ xo0, float* __restrict__ s1o, float* __restrict__ s2o) {
    __shared__ float elurow[4][512];
    int tid = threadIdx.x;
    int w = tid >> 6, lane = tid & 63;
    int n = blockIdx.x * 4 + w;
    int nn = n < NN ? n : NN - 1;
    const float* hpr = hp + (size_t)nn * NF;
    float rs = rowsum[nn * 4 + (lane >> 4)] + EPSF;   // lane*8..lane*8+7 same factor
    float4 h0 = *(const float4*)(hpr + lane * 8);
    float4 h1 = *(const float4*)(hpr + lane * 8 + 4);
    float v[8] = {h0.x, h0.y, h0.z, h0.w, h1.x, h1.y, h1.z, h1.w};
#pragma unroll
    for (int i = 0; i < 8; ++i) {
        float t = v[i] / rs;
        v[i] = t > 0.f ? t : expm1f(t);
    }
    *(float4*)&elurow[w][lane * 8]     = make_float4(v[0], v[1], v[2], v[3]);
    *(float4*)&elurow[w][lane * 8 + 4] = make_float4(v[4], v[5], v[6], v[7]);
    __syncthreads();
    const float* er = elurow[w];
    float acc = 0.f;
#pragma unroll 8
    for (int j = 0; j < 512; ++j) acc = fmaf(er[j], Wo[j * 64 + lane], acc);
    float p1 = acc * a_out[lane];
    float p2 = acc * a_out[64 + lane];
#pragma unroll
    for (int off = 32; off >= 1; off >>= 1) {
        p1 += __shfl_xor(p1, off);
        p2 += __shfl_xor(p2, off);
    }
    if (n < NN) {
        xo0[(size_t)n * NC + lane] = acc;
        if (lane == 0) { s1o[n] = p1; s2o[n] = p2; }
    }
}

// ---------------------------------------------------------------------------
// K6: layer-2 per-edge e-values at CSR positions (src recovered from rec).
__global__ __launch_bounds__(256) void edge_pre2(
        const int4* __restrict__ rec, const float* __restrict__ s1o,
        const float* __restrict__ s2o, float* __restrict__ eeo) {
    int p = blockIdx.x * 256 + threadIdx.x;
    if (p >= NE) return;
    int4 r = rec[p];
    int src = r.y & 0xFFFF;
    float sv = s1o[src] + s2o[r.x];
    eeo[p] = expf(-(sv >= 0.f ? sv : LRELU_ALPHA * sv));
}

// ---------------------------------------------------------------------------
// K7: output attention gather fused with elu + log-softmax. Wave per node.
__global__ __launch_bounds__(256) void node_gather2(
        const int* __restrict__ start, const int4* __restrict__ rec,
        const float* __restrict__ eeo, const float* __restrict__ xo0,
        float* __restrict__ out) {
    int w = threadIdx.x >> 6, lane = threadIdx.x & 63;
    int n = blockIdx.x * 4 + w;
    if (n >= NN) return;
    int j0 = start[n], j1 = start[n + 1];
    float acc = 0.f, rsum = 0.f;
    int j = j0;
    for (; j + 1 < j1; j += 2) {
        int da = rec[j].x;     float ea = eeo[j];
        int db = rec[j + 1].x; float eb = eeo[j + 1];
        acc = fmaf(ea, xo0[(size_t)da * NC + lane], acc);
        acc = fmaf(eb, xo0[(size_t)db * NC + lane], acc);
        rsum += ea + eb;
    }
    if (j < j1) {
        int da = rec[j].x; float ea = eeo[j];
        acc = fmaf(ea, xo0[(size_t)da * NC + lane], acc);
        rsum += ea;
    }
    float t = acc / (rsum + EPSF);
    float v = t > 0.f ? t : expm1f(t);
    float m = v;
#pragma unroll
    for (int off = 32; off >= 1; off >>= 1) m = fmaxf(m, __shfl_xor(m, off));
    float p = expf(v - m);
#pragma unroll
    for (int off = 32; off >= 1; off >>= 1) p += __shfl_xor(p, off);
    out[(size_t)n * NC + lane] = v - m - logf(p);
}

__global__ void finalize_att(const double* __restrict__ att_acc, float* __restrict__ out) {
    out[(size_t)NN * NC] = 1.f - (float)(att_acc[0] / (double)NE);
}

// ---------------------------------------------------------------------------
extern "C" void kernel_launch(void* const* d_in, const int* in_sizes, int n_in,
                              void* d_out, int out_size, void* d_ws, size_t ws_size,
                              hipStream_t stream) {
    const float* x     = (const float*)d_in[0];
    const int*   edge  = (const int*)d_in[1];
    const float* Wks   = (const float*)d_in[2];
    const float* a_k   = (const float*)d_in[3];
    const float* Wo    = (const float*)d_in[4];
    const float* a_att = (const float*)d_in[5];
    const float* a_out = (const float*)d_in[6];
    float* out = (float*)d_out;

    float* wsf = (float*)d_ws;
    float* h      = wsf + OFF_H;
    float* hp     = wsf + OFF_HP;
    int4*  rec    = (int4*)(wsf + OFF_REC);
    float* xo0    = wsf + OFF_XO0;
    float* eeo    = wsf + OFF_EEO;
    float* s_src  = wsf + OFF_SSRC;
    float* s_dst  = wsf + OFF_SDST;
    float* s1a    = wsf + OFF_S1A;
    float* s2a    = wsf + OFF_S2A;
    float* rowsum = wsf + OFF_ROWSUM;
    float* s1o    = wsf + OFF_S1O;
    float* s2o    = wsf + OFF_S2O;
    int*   startp = (int*)(wsf + OFF_START);
    int*   cnt    = (int*)(wsf + OFF_CNT);
    int*   cursor = (int*)(wsf + OFF_CURSOR);
    double* att   = (double*)(wsf + OFF_ATT);

    // zero only the accumulation region (cnt, cursor, att) every call
    size_t zero_bytes = (size_t)(WS_FLOATS - OFF_CNT) * sizeof(float);
    hipMemsetAsync((char*)d_ws + (size_t)OFF_CNT * sizeof(float), 0, zero_bytes, stream);

    gemm_h<<<dim3(NF / 64, (NN + 63) / 64), 256, 0, stream>>>(x, Wks, h);
    compute_svals_h<<<(NN + 3) / 4, 256, 0, stream>>>(h, a_k, a_att,
                                                      s_src, s_dst, s1a, s2a);
    csr_count<<<(NE + 255) / 256, 256, 0, stream>>>(edge, cnt);
    csr_scan<<<1, 1024, 0, stream>>>(cnt, startp);
    edge_pre1<<<(NE + 255) / 256, 256, 0, stream>>>(edge, startp, cursor,
                                                    s_src, s_dst, s1a, s2a, rec, att);
    node_gather1<<<NN, 256, 0, stream>>>(startp, rec, h, hp, rowsum);
    node_pass<<<(NN + 3) / 4, 256, 0, stream>>>(hp, rowsum, Wo, a_out, xo0, s1o, s2o);
    edge_pre2<<<(NE + 255) / 256, 256, 0, stream>>>(rec, s1o, s2o, eeo);
    node_gather2<<<(NN + 3) / 4, 256, 0, stream>>>(startp, rec, eeo, xo0, out);
    finalize_att<<<1, 1, 0, stream>>>(att, out);
}

// Round 4
// 894.723 us; speedup vs baseline: 4.5513x; 1.1424x over previous
//
#include <hip/hip_runtime.h>
#include <math.h>

#define NN 50000
#define NE 800000
#define NF 512
#define NH 128
#define KF 4
#define NC 64
#define LRELU_ALPHA 0.2f
#define EPSF 1e-16f

// ---------------- workspace layout (float offsets) ----------------
#define OFF_H      0LL                                  // h (NN,512)
#define OFF_HP     (OFF_H + (long long)NN * NF)         // hp (NN,512)
#define OFF_REC    (OFF_HP + (long long)NN * NF)        // rec (NE int4) 16B aligned
#define OFF_XO0    (OFF_REC + 4LL * NE)                 // (NN,64)
#define OFF_EEO    (OFF_XO0 + (long long)NN * NC)       // (NE,)
#define OFF_SSRC   (OFF_EEO + (long long)NE)            // (NN,4)
#define OFF_SDST   (OFF_SSRC + (long long)NN * KF)
#define OFF_S1A    (OFF_SDST + (long long)NN * KF)
#define OFF_S2A    (OFF_S1A + (long long)NN * KF)
#define OFF_ROWSUM (OFF_S2A + (long long)NN * KF)       // (NN,4)
#define OFF_S1O    (OFF_ROWSUM + (long long)NN * KF)    // (NN,)
#define OFF_S2O    (OFF_S1O + NN)
#define OFF_START  (OFF_S2O + NN)                       // (NN+1) ints, pad to even+2
// ---- zeroed-each-call region starts here ----
#define OFF_CNT    (OFF_START + NN + 4)                 // NN ints
#define OFF_CURSOR (OFF_CNT + NN)                       // NN ints
#define OFF_ATT    (OFF_CURSOR + NN)                    // double (2 floats), 8B-aligned
#define WS_FLOATS  (OFF_ATT + 2)

// ---------------------------------------------------------------------------
// K1: h = x @ Wcat (f32), 128x128 tile, BK=16, 256 threads, 8x8 microtile.
// k-accumulation strictly sequential 0..511 per output -> h bitwise identical
// to previous rounds (top-2 factor selection cannot flip).
__global__ __launch_bounds__(256) void gemm_h(const float* __restrict__ x,
                                              const float* __restrict__ Wks,
                                              float* __restrict__ h) {
    __shared__ float As[16][128];   // transposed A tile: As[k][m]
    __shared__ float Bs[16][132];   // +4 pad spreads staging-write banks
    int m0 = blockIdx.y * 128;
    int n0 = blockIdx.x * 128;      // n0/128 = factor index, cols 0..127 of it
    const float* Bsrc = Wks + (size_t)(n0 >> 7) * (NF * NH);  // [f][j], j stride 1
    int tid = threadIdx.x;
    int tm = tid >> 4, tn = tid & 15;
    float acc[8][8];
#pragma unroll
    for (int i = 0; i < 8; ++i)
#pragma unroll
        for (int j = 0; j < 8; ++j) acc[i][j] = 0.f;

    int arow = tid >> 1;            // 0..127
    int akc  = (tid & 1) * 8;       // 0 or 8
    int am = m0 + arow; if (am >= NN) am = NN - 1;   // clamp; OOB rows not stored
    int brow = tid >> 4;            // 0..15
    int bcol = (tid & 15) * 8;      // 0..120

    for (int k0 = 0; k0 < NF; k0 += 16) {
        float4 a0 = *(const float4*)(x + (size_t)am * NF + k0 + akc);
        float4 a1 = *(const float4*)(x + (size_t)am * NF + k0 + akc + 4);
        As[akc + 0][arow] = a0.x; As[akc + 1][arow] = a0.y;
        As[akc + 2][arow] = a0.z; As[akc + 3][arow] = a0.w;
        As[akc + 4][arow] = a1.x; As[akc + 5][arow] = a1.y;
        As[akc + 6][arow] = a1.z; As[akc + 7][arow] = a1.w;
        float4 b0 = *(const float4*)(Bsrc + (size_t)(k0 + brow) * NH + bcol);
        float4 b1 = *(const float4*)(Bsrc + (size_t)(k0 + brow) * NH + bcol + 4);
        *(float4*)&Bs[brow][bcol]     = b0;
        *(float4*)&Bs[brow][bcol + 4] = b1;
        __syncthreads();
#pragma unroll
        for (int kk = 0; kk < 16; ++kk) {
            float4 av0 = *(float4*)&As[kk][tm * 8];
            float4 av1 = *(float4*)&As[kk][tm * 8 + 4];
            float4 bv0 = *(float4*)&Bs[kk][tn * 4];
            float4 bv1 = *(float4*)&Bs[kk][64 + tn * 4];
            float a[8] = {av0.x, av0.y, av0.z, av0.w, av1.x, av1.y, av1.z, av1.w};
            float b[8] = {bv0.x, bv0.y, bv0.z, bv0.w, bv1.x, bv1.y, bv1.z, bv1.w};
#pragma unroll
            for (int i = 0; i < 8; ++i)
#pragma unroll
                for (int j = 0; j < 8; ++j)
                    acc[i][j] = fmaf(a[i], b[j], acc[i][j]);
        }
        __syncthreads();
    }
#pragma unroll
    for (int i = 0; i < 8; ++i) {
        int m = m0 + tm * 8 + i;
        if (m < NN) {
            float4 o0 = make_float4(acc[i][0], acc[i][1], acc[i][2], acc[i][3]);
            float4 o1 = make_float4(acc[i][4], acc[i][5], acc[i][6], acc[i][7]);
            *(float4*)(h + (size_t)m * NF + n0 + tn * 4)      = o0;
            *(float4*)(h + (size_t)m * NF + n0 + 64 + tn * 4) = o1;
        }
    }
}

// ---------------------------------------------------------------------------
// K2: routing/attention scalars from h (matches reference contraction h @ a).
__global__ __launch_bounds__(256) void compute_svals_h(
        const float* __restrict__ h, const float* __restrict__ a_k,
        const float* __restrict__ a_att,
        float* __restrict__ s_src, float* __restrict__ s_dst,
        float* __restrict__ s1a, float* __restrict__ s2a) {
    __shared__ float Ak[4][1024];
    __shared__ float Aa[4][256];
    for (int i = threadIdx.x; i < 4096; i += 256) Ak[i >> 10][i & 1023] = a_k[i];
    for (int i = threadIdx.x; i < 1024; i += 256) Aa[i >> 8][i & 255] = a_att[i];
    __syncthreads();
    int w = threadIdx.x >> 6, lane = threadIdx.x & 63;
    int n = blockIdx.x * 4 + w;
    if (n >= NN) return;
    const float* hr = h + (size_t)n * NF;
    float accS[4] = {0, 0, 0, 0}, accD[4] = {0, 0, 0, 0};
    float accQ1[4] = {0, 0, 0, 0}, accQ2[4] = {0, 0, 0, 0};
#pragma unroll
    for (int i = 0; i < 8; ++i) {
        int f = i * 64 + lane;
        float hv = hr[f];
#pragma unroll
        for (int k = 0; k < 4; ++k) {
            accS[k] = fmaf(hv, Ak[k][f], accS[k]);
            accD[k] = fmaf(hv, Ak[k][512 + f], accD[k]);
        }
        accQ1[i >> 1] = fmaf(hv, Aa[i >> 1][f & 127], accQ1[i >> 1]);
        accQ2[i >> 1] = fmaf(hv, Aa[i >> 1][128 + (f & 127)], accQ2[i >> 1]);
    }
#pragma unroll
    for (int off = 32; off >= 1; off >>= 1) {
#pragma unroll
        for (int k = 0; k < 4; ++k) {
            accS[k] += __shfl_xor(accS[k], off);
            accD[k] += __shfl_xor(accD[k], off);
            accQ1[k] += __shfl_xor(accQ1[k], off);
            accQ2[k] += __shfl_xor(accQ2[k], off);
        }
    }
    if (lane == 0) {
#pragma unroll
        for (int k = 0; k < 4; ++k) {
            s_src[n * 4 + k] = accS[k];
            s_dst[n * 4 + k] = accD[k];
            s1a[n * 4 + k]   = accQ1[k];
            s2a[n * 4 + k]   = accQ2[k];
        }
    }
}

// ---------------------------------------------------------------------------
// CSR build: count / scan
__global__ void csr_count(const int* __restrict__ edge, int* __restrict__ cnt) {
    int e = blockIdx.x * 256 + threadIdx.x;
    if (e < NE) atomicAdd(&cnt[edge[e]], 1);
}

__global__ __launch_bounds__(1024) void csr_scan(const int* __restrict__ cnt,
                                                 int* __restrict__ start) {
    __shared__ int part[1024];
    int t = threadIdx.x;
    const int CH = (NN + 1023) / 1024;  // 49
    int base = t * CH;
    int s = 0;
    for (int i = 0; i < CH; ++i) {
        int idx = base + i;
        if (idx < NN) s += cnt[idx];
    }
    part[t] = s;
    __syncthreads();
    for (int off = 1; off < 1024; off <<= 1) {
        int v = (t >= off) ? part[t - off] : 0;
        __syncthreads();
        part[t] += v;
        __syncthreads();
    }
    int run = (t == 0) ? 0 : part[t - 1];
    for (int i = 0; i < CH; ++i) {
        int idx = base + i;
        if (idx < NN) { start[idx] = run; run += cnt[idx]; }
    }
    if (t == 1023) start[NN] = run;
}

// ---------------------------------------------------------------------------
// K3: edge-parallel scalar precompute + CSR fill. One thread per edge.
__global__ __launch_bounds__(256) void edge_pre1(
        const int* __restrict__ edge, const int* __restrict__ start,
        int* __restrict__ cursor,
        const float* __restrict__ s_src, const float* __restrict__ s_dst,
        const float* __restrict__ s1a, const float* __restrict__ s2a,
        int4* __restrict__ rec, double* __restrict__ att_acc) {
    __shared__ float blk[4];
    int tid = threadIdx.x;
    int e = blockIdx.x * 256 + tid;
    float t2 = 0.f;
    if (e < NE) {
        int src = edge[e];
        int dst = edge[NE + e];
        float4 ss = *(const float4*)(s_src + (size_t)src * 4);
        float4 sd = *(const float4*)(s_dst + (size_t)dst * 4);
        float l0 = ss.x + sd.x, l1 = ss.y + sd.y, l2 = ss.z + sd.z, l3 = ss.w + sd.w;
        int i1 = 0; float v1 = l0;
        if (l1 > v1) { v1 = l1; i1 = 1; }
        if (l2 > v1) { v1 = l2; i1 = 2; }
        if (l3 > v1) { v1 = l3; i1 = 3; }
        int i2 = 0; float v2 = -3.4e38f;
        if (i1 != 0)            { v2 = l0; i2 = 0; }
        if (i1 != 1 && l1 > v2) { v2 = l1; i2 = 1; }
        if (i1 != 2 && l2 > v2) { v2 = l2; i2 = 2; }
        if (i1 != 3 && l3 > v2) { v2 = l3; i2 = 3; }
        float esum = expf(l0 - v1) + expf(l1 - v1) + expf(l2 - v1) + expf(l3 - v1);
        t2 = (1.f + expf(v2 - v1)) / esum;
        float4 q1 = *(const float4*)(s1a + (size_t)src * 4);
        float4 q2 = *(const float4*)(s2a + (size_t)dst * 4);
        float q1v1 = i1 == 0 ? q1.x : i1 == 1 ? q1.y : i1 == 2 ? q1.z : q1.w;
        float q2v1 = i1 == 0 ? q2.x : i1 == 1 ? q2.y : i1 == 2 ? q2.z : q2.w;
        float q1v2 = i2 == 0 ? q1.x : i2 == 1 ? q1.y : i2 == 2 ? q1.z : q1.w;
        float q2v2 = i2 == 0 ? q2.x : i2 == 1 ? q2.y : i2 == 2 ? q2.z : q2.w;
        float sv1 = q1v1 + q2v1, sv2 = q1v2 + q2v2;
        float ee1 = expf(-(sv1 >= 0.f ? sv1 : LRELU_ALPHA * sv1));
        float ee2 = expf(-(sv2 >= 0.f ? sv2 : LRELU_ALPHA * sv2));
        int p = start[src] + atomicAdd(&cursor[src], 1);
        rec[p] = make_int4(dst, src | (i1 << 16) | (i2 << 18),
                           __float_as_int(ee1), __float_as_int(ee2));
    }
#pragma unroll
    for (int off = 32; off >= 1; off >>= 1) t2 += __shfl_xor(t2, off);
    if ((tid & 63) == 0) blk[tid >> 6] = t2;
    __syncthreads();
    if (tid == 0)
        atomicAdd(att_acc, (double)(blk[0] + blk[1] + blk[2] + blk[3]));
}

// ---------------------------------------------------------------------------
// K4: layer-1 gather. One block per node, one wave per factor.
__global__ __launch_bounds__(256) void node_gather1(
        const int* __restrict__ start, const int4* __restrict__ rec,
        const float* __restrict__ h, float* __restrict__ hp,
        float* __restrict__ rowsum) {
    int n = blockIdx.x;
    int k = threadIdx.x >> 6;
    int lane = threadIdx.x & 63;
    int j0 = start[n], j1 = start[n + 1];
    const float* hbase = h + (size_t)k * NH + lane;
    float a0 = 0.f, a1 = 0.f, rs = 0.f;
    int j = j0;
    for (; j + 1 < j1; j += 2) {
        int4 ra = rec[j];
        int4 rb = rec[j + 1];
        int i1a = (ra.y >> 16) & 3, i2a = (ra.y >> 18) & 3;
        int i1b = (rb.y >> 16) & 3, i2b = (rb.y >> 18) & 3;
        float wa = (i1a == k) ? __int_as_float(ra.z)
                 : (i2a == k) ? __int_as_float(ra.w) : 0.f;
        float wb = (i1b == k) ? __int_as_float(rb.z)
                 : (i2b == k) ? __int_as_float(rb.w) : 0.f;
        if (wa != 0.f) {
            const float* hr = hbase + (size_t)ra.x * NF;
            a0 = fmaf(wa, hr[0], a0);
            a1 = fmaf(wa, hr[64], a1);
            rs += wa;
        }
        if (wb != 0.f) {
            const float* hr = hbase + (size_t)rb.x * NF;
            a0 = fmaf(wb, hr[0], a0);
            a1 = fmaf(wb, hr[64], a1);
            rs += wb;
        }
    }
    if (j < j1) {
        int4 ra = rec[j];
        int i1a = (ra.y >> 16) & 3, i2a = (ra.y >> 18) & 3;
        float wa = (i1a == k) ? __int_as_float(ra.z)
                 : (i2a == k) ? __int_as_float(ra.w) : 0.f;
        if (wa != 0.f) {
            const float* hr = hbase + (size_t)ra.x * NF;
            a0 = fmaf(wa, hr[0], a0);
            a1 = fmaf(wa, hr[64], a1);
            rs += wa;
        }
    }
    float* hpr = hp + (size_t)n * NF + k * NH;
    hpr[lane]      = a0;
    hpr[64 + lane] = a1;
    if (lane == 0) rowsum[n * 4 + k] = rs;
}

// ---------------------------------------------------------------------------
// K5: node pass as tiled GEMM. out_cat = elu(hp/(rowsum+eps)) fused into the
// A-staging; xo0 = out_cat @ W_o (128x64 tile, BK=16, 8x4 microtile);
// s1o/s2o = xo0 . a_out halves computed in the epilogue (16-lane shfl reduce).
// k-order sequential 0..511 -> xo0 bitwise identical to the old node_pass.
__global__ __launch_bounds__(256) void node_pass_gemm(
        const float* __restrict__ hp, const float* __restrict__ rowsum,
        const float* __restrict__ Wo, const float* __restrict__ a_out,
        float* __restrict__ xo0, float* __restrict__ s1o, float* __restrict__ s2o) {
    __shared__ float As[16][128];
    __shared__ float Bs[16][64];
    int m0 = blockIdx.x * 128;
    int tid = threadIdx.x;
    int tm = tid >> 4, tn = tid & 15;
    float acc[8][4];
#pragma unroll
    for (int i = 0; i < 8; ++i)
#pragma unroll
        for (int j = 0; j < 4; ++j) acc[i][j] = 0.f;

    int arow = tid >> 1;
    int akc  = (tid & 1) * 8;
    int am = m0 + arow; if (am >= NN) am = NN - 1;
    int brow = tid >> 4, bcol = (tid & 15) * 4;

    for (int k0 = 0; k0 < NF; k0 += 16) {
        float rs = rowsum[am * 4 + ((k0 + akc) >> 7)] + EPSF;
        float4 v0 = *(const float4*)(hp + (size_t)am * NF + k0 + akc);
        float4 v1 = *(const float4*)(hp + (size_t)am * NF + k0 + akc + 4);
        float v[8] = {v0.x, v0.y, v0.z, v0.w, v1.x, v1.y, v1.z, v1.w};
#pragma unroll
        for (int i = 0; i < 8; ++i) {
            float t = v[i] / rs;
            v[i] = t > 0.f ? t : expm1f(t);
        }
        As[akc + 0][arow] = v[0]; As[akc + 1][arow] = v[1];
        As[akc + 2][arow] = v[2]; As[akc + 3][arow] = v[3];
        As[akc + 4][arow] = v[4]; As[akc + 5][arow] = v[5];
        As[akc + 6][arow] = v[6]; As[akc + 7][arow] = v[7];
        *(float4*)&Bs[brow][bcol] =
            *(const float4*)(Wo + (size_t)(k0 + brow) * NC + bcol);
        __syncthreads();
#pragma unroll
        for (int kk = 0; kk < 16; ++kk) {
            float4 av0 = *(float4*)&As[kk][tm * 8];
            float4 av1 = *(float4*)&As[kk][tm * 8 + 4];
            float4 bv  = *(float4*)&Bs[kk][tn * 4];
            float a[8] = {av0.x, av0.y, av0.z, av0.w, av1.x, av1.y, av1.z, av1.w};
            float b[4] = {bv.x, bv.y, bv.z, bv.w};
#pragma unroll
            for (int i = 0; i < 8; ++i)
#pragma unroll
                for (int j = 0; j < 4; ++j)
                    acc[i][j] = fmaf(a[i], b[j], acc[i][j]);
        }
        __syncthreads();
    }
    float4 ao1 = *(const float4*)(a_out + tn * 4);
    float4 ao2 = *(const float4*)(a_out + 64 + tn * 4);
#pragma unroll
    for (int i = 0; i < 8; ++i) {
        int m = m0 + tm * 8 + i;
        float4 o = make_float4(acc[i][0], acc[i][1], acc[i][2], acc[i][3]);
        float p1 = o.x * ao1.x + o.y * ao1.y + o.z * ao1.z + o.w * ao1.w;
        float p2 = o.x * ao2.x + o.y * ao2.y + o.z * ao2.z + o.w * ao2.w;
#pragma unroll
        for (int off = 8; off >= 1; off >>= 1) {  // reduce across 16 tn lanes
            p1 += __shfl_xor(p1, off);
            p2 += __shfl_xor(p2, off);
        }
        if (m < NN) {
            *(float4*)(xo0 + (size_t)m * NC + tn * 4) = o;
            if (tn == 0) { s1o[m] = p1; s2o[m] = p2; }
        }
    }
}

// ---------------------------------------------------------------------------
// K6: layer-2 per-edge e-values at CSR positions (src recovered from rec).
__global__ __launch_bounds__(256) void edge_pre2(
        const int4* __restrict__ rec, const float* __restrict__ s1o,
        const float* __restrict__ s2o, float* __restrict__ eeo) {
    int p = blockIdx.x * 256 + threadIdx.x;
    if (p >= NE) return;
    int4 r = rec[p];
    int src = r.y & 0xFFFF;
    float sv = s1o[src] + s2o[r.x];
    eeo[p] = expf(-(sv >= 0.f ? sv : LRELU_ALPHA * sv));
}

// ---------------------------------------------------------------------------
// K7: output attention gather fused with elu + log-softmax. Wave per node.
__global__ __launch_bounds__(256) void node_gather2(
        const int* __restrict__ start, const int4* __restrict__ rec,
        const float* __restrict__ eeo, const float* __restrict__ xo0,
        float* __restrict__ out) {
    int w = threadIdx.x >> 6, lane = threadIdx.x & 63;
    int n = blockIdx.x * 4 + w;
    if (n >= NN) return;
    int j0 = start[n], j1 = start[n + 1];
    float acc = 0.f, rsum = 0.f;
    int j = j0;
    for (; j + 1 < j1; j += 2) {
        int da = rec[j].x;     float ea = eeo[j];
        int db = rec[j + 1].x; float eb = eeo[j + 1];
        acc = fmaf(ea, xo0[(size_t)da * NC + lane], acc);
        acc = fmaf(eb, xo0[(size_t)db * NC + lane], acc);
        rsum += ea + eb;
    }
    if (j < j1) {
        int da = rec[j].x; float ea = eeo[j];
        acc = fmaf(ea, xo0[(size_t)da * NC + lane], acc);
        rsum += ea;
    }
    float t = acc / (rsum + EPSF);
    float v = t > 0.f ? t : expm1f(t);
    float m = v;
#pragma unroll
    for (int off = 32; off >= 1; off >>= 1) m = fmaxf(m, __shfl_xor(m, off));
    float p = expf(v - m);
#pragma unroll
    for (int off = 32; off >= 1; off >>= 1) p += __shfl_xor(p, off);
    out[(size_t)n * NC + lane] = v - m - logf(p);
}

__global__ void finalize_att(const double* __restrict__ att_acc, float* __restrict__ out) {
    out[(size_t)NN * NC] = 1.f - (float)(att_acc[0] / (double)NE);
}

// ---------------------------------------------------------------------------
extern "C" void kernel_launch(void* const* d_in, const int* in_sizes, int n_in,
                              void* d_out, int out_size, void* d_ws, size_t ws_size,
                              hipStream_t stream) {
    const float* x     = (const float*)d_in[0];
    const int*   edge  = (const int*)d_in[1];
    const float* Wks   = (const float*)d_in[2];
    const float* a_k   = (const float*)d_in[3];
    const float* Wo    = (const float*)d_in[4];
    const float* a_att = (const float*)d_in[5];
    const float* a_out = (const float*)d_in[6];
    float* out = (float*)d_out;

    float* wsf = (float*)d_ws;
    float* h      = wsf + OFF_H;
    float* hp     = wsf + OFF_HP;
    int4*  rec    = (int4*)(wsf + OFF_REC);
    float* xo0    = wsf + OFF_XO0;
    float* eeo    = wsf + OFF_EEO;
    float* s_src  = wsf + OFF_SSRC;
    float* s_dst  = wsf + OFF_SDST;
    float* s1a    = wsf + OFF_S1A;
    float* s2a    = wsf + OFF_S2A;
    float* rowsum = wsf + OFF_ROWSUM;
    float* s1o    = wsf + OFF_S1O;
    float* s2o    = wsf + OFF_S2O;
    int*   startp = (int*)(wsf + OFF_START);
    int*   cnt    = (int*)(wsf + OFF_CNT);
    int*   cursor = (int*)(wsf + OFF_CURSOR);
    double* att   = (double*)(wsf + OFF_ATT);

    // zero only the accumulation region (cnt, cursor, att) every call
    size_t zero_bytes = (size_t)(WS_FLOATS - OFF_CNT) * sizeof(float);
    hipMemsetAsync((char*)d_ws + (size_t)OFF_CNT * sizeof(float), 0, zero_bytes, stream);

    gemm_h<<<dim3(4, (NN + 127) / 128), 256, 0, stream>>>(x, Wks, h);
    compute_svals_h<<<(NN + 3) / 4, 256, 0, stream>>>(h, a_k, a_att,
                                                      s_src, s_dst, s1a, s2a);
    csr_count<<<(NE + 255) / 256, 256, 0, stream>>>(edge, cnt);
    csr_scan<<<1, 1024, 0, stream>>>(cnt, startp);
    edge_pre1<<<(NE + 255) / 256, 256, 0, stream>>>(edge, startp, cursor,
                                                    s_src, s_dst, s1a, s2a, rec, att);
    node_gather1<<<NN, 256, 0, stream>>>(startp, rec, h, hp, rowsum);
    node_pass_gemm<<<(NN + 127) / 128, 256, 0, stream>>>(hp, rowsum, Wo, a_out,
                                                         xo0, s1o, s2o);
    edge_pre2<<<(NE + 255) / 256, 256, 0, stream>>>(rec, s1o, s2o, eeo);
    node_gather2<<<(NN + 3) / 4, 256, 0, stream>>>(startp, rec, eeo, xo0, out);
    finalize_att<<<1, 1, 0, stream>>>(att, out);
}